// Round 4
// baseline (170.524 us; speedup 1.0000x reference)
//
#include <hip/hip_runtime.h>
#include <hip/hip_bf16.h>

namespace {

typedef __attribute__((ext_vector_type(8))) short bh8;   // 8 bf16 = 4 VGPR MFMA A/B frag
typedef __attribute__((ext_vector_type(4))) short sh4;   // 4 bf16 (8B)
typedef __attribute__((ext_vector_type(4))) float fx4;

constexpr int Rn = 96, Cn = 64, CINn = 8, COUTn = 64;
constexpr int NPOS   = 8 * 96 * 64 * 8;     // 393216 positions
constexpr int PPG    = 8 * 96 * 64;         // 49152 positions per g
constexpr int NCH    = 6;                   // chunks of 16 rows
// ws layout (bytes)
constexpr size_t FEAT_OFF = 0;                                // bf16x8 per pos, g-major: 6.29 MB
constexpr size_t FWT_OFF  = (size_t)NPOS * 16;                // FwT bf16 [g][o][r][i]: 6.29 MB
constexpr size_t CA_OFF   = FWT_OFF + (size_t)NPOS * 16;      // convA bf16 [g][co][64]: 64 KB
constexpr size_t PART_OFF = CA_OFF + 65536;                   // partials f32 [3072][1024]: 12.6 MB

__device__ inline ushort f2b(float f) {
  __hip_bfloat16 h = __float2bfloat16(f);
  return __builtin_bit_cast(ushort, h);
}
__device__ inline float b2f(ushort u) {
  return __builtin_bit_cast(float, (unsigned)u << 16);
}
__device__ inline bh8 pack8(const float* v) {
  bh8 r;
#pragma unroll
  for (int j = 0; j < 8; ++j) r[j] = (short)f2b(v[j]);
  return r;
}
// swizzled byte offset into a [16 bc][16 pos][64 i] bf16 buffer (128B rows)
__device__ inline int swz(int bc, int pos, int ib) {
  return (bc * 2048 + pos * 128 + ib) ^ (((pos + bc) & 7) << 4);
}

#define MFMA16(a, b, c) __builtin_amdgcn_mfma_f32_16x16x32_bf16((a), (b), (c), 0, 0, 0)

// ================= pre-pass: feat pack (g-major), FwT transpose, convA pack =================
__global__ __launch_bounds__(256)
void cvt_k(const float* __restrict__ x, const float* __restrict__ xm,
           const float* __restrict__ Fw, const float* __restrict__ Wd,
           const float* __restrict__ bd, const float* __restrict__ Wm,
           const float* __restrict__ bm, ushort* __restrict__ feat,
           ushort* __restrict__ FwT, ushort* __restrict__ cA)
{
  const int bid = blockIdx.x, t = threadIdx.x;
  if (bid < NPOS / 256) {
    // feat[g][pb] = [x, xm0..3, 1, 0, 0] bf16
    const int opos = bid * 256 + t;
    const int g = opos / PPG, pb = opos - g * PPG;
    const size_t in = (size_t)pb * 8 + g;
    const float xs = x[in];
    const fx4 m = *(const fx4*)(xm + in * 4);
    bh8 o;
    o[0] = (short)f2b(xs);
    o[1] = (short)f2b(m[0]); o[2] = (short)f2b(m[1]);
    o[3] = (short)f2b(m[2]); o[4] = (short)f2b(m[3]);
    o[5] = (short)0x3F80; o[6] = 0; o[7] = 0;
    *(bh8*)(feat + (size_t)opos * 8) = o;
  } else if (bid < NPOS / 256 + 512) {
    // FwT[g][o][r][i] <- Fw[g][o][i][r], LDS tile transpose per (g,o)
    __shared__ float tile[64 * 97];
    const int go = bid - NPOS / 256;
    const float* src = Fw + (size_t)go * 6144;
    for (int idx = t; idx < 6144; idx += 256) tile[(idx / 96) * 97 + (idx % 96)] = src[idx];
    __syncthreads();
    ushort* dst = FwT + (size_t)go * 6144;
    for (int idx = t; idx < 6144; idx += 256) {
      const int r = idx >> 6, i = idx & 63;
      dst[idx] = f2b(tile[i * 97 + r]);
    }
  } else {
    // convA[g][co][k=tap*8+tch]
    for (int e = t; e < 32768; e += 256) {
      const int g = e >> 12, co = (e >> 6) & 63, k = e & 63;
      const int tap = k >> 3, tch = k & 7;
      float v = 0.f;
      if (tch == 0)      v = Wd[(g * 64 + co) * 8 + tap];
      else if (tch <= 4) v = Wm[((g * 64 + co) * 4 + (tch - 1)) * 8 + tap];
      else if (tch == 5 && tap == 0) v = bd[g * 64 + co] + bm[g * 64 + co];
      cA[e] = f2b(v);
    }
  }
}

// ================= main: conv -> gate -> fc partial (one 16-row chunk per block) =================
__global__ __launch_bounds__(512, 4)
void fused_v4(const float* __restrict__ Gd, const float* __restrict__ bgd,
              const float* __restrict__ Gm, const float* __restrict__ bgm,
              const float* __restrict__ Gh, const float* __restrict__ bgh,
              const ushort* __restrict__ feat, const ushort* __restrict__ FwT,
              const ushort* __restrict__ cA, float* __restrict__ part)
{
  __shared__ __align__(16) char sHid[32768];   // [16bc][16pos][64i] bf16, swizzled
  __shared__ __align__(16) char sGat[32768];   // gated hid, same layout

  const int t    = threadIdx.x;
  const int lane = t & 63;
  const int w    = t >> 6;
  const int il   = lane >> 4;
  const int mr   = lane & 15;
  const int bid  = blockIdx.x;
  const int g    = bid & 7;                    // XCD-affine
  const int bcT  = (bid >> 3) & 31;
  const int ch   = bid >> 8;                   // 0..5
  const int r0   = ch * 16;
  const ushort* fg = feat + (size_t)g * PPG * 8;

  // ---------- conv phase: wave w owns bc {2w, 2w+1} ----------
  {
    bh8 aC[4][2];
    const ushort* cAg = cA + g * 4096;
#pragma unroll
    for (int s = 0; s < 4; ++s)
#pragma unroll
      for (int hh = 0; hh < 2; ++hh)
        aC[s][hh] = *(const bh8*)(cAg + (s * 16 + mr) * 64 + hh * 32 + 8 * il);

#pragma unroll
    for (int bci = 0; bci < 2; ++bci) {
      const int bcl = 2 * w + bci;
      const int bcg = bcT * 16 + bcl;
      const int bb = bcg >> 6, cc_ = bcg & 63;
      const int q0 = r0 + mr - 8 + il;
      const int q1 = q0 + 4;
      const bh8 zpad = {0, 0, 0, 0, 0, (short)0x3F80, 0, 0};
      const bh8 b0 = (q0 >= 0) ? *(const bh8*)(fg + (size_t)((bb * 96 + q0) * 64 + cc_) * 8) : zpad;
      const bh8 b1 = (q1 >= 0) ? *(const bh8*)(fg + (size_t)((bb * 96 + q1) * 64 + cc_) * 8) : zpad;
#pragma unroll
      for (int s = 0; s < 4; ++s) {
        fx4 a = {0.f, 0.f, 0.f, 0.f};
        a = MFMA16(aC[s][0], b0, a);
        a = MFMA16(aC[s][1], b1, a);
        sh4 o4;
#pragma unroll
        for (int cc = 0; cc < 4; ++cc) o4[cc] = (short)f2b(a[cc]);
        *(sh4*)(sHid + swz(bcl, mr, s * 32 + il * 8)) = o4;
      }
    }
  }
  __syncthreads();   // B1: sHid complete

  // ---------- gate phase: pair p=w>>1 owns bc {4p..4p+3}; half hw=w&1 owns s {2hw,2hw+1} ----------
  {
    const int hw = w & 1;
    bh8 gA[12];   // [ss]{aS0,aS1,aSx,aT0,aT1,aTx}
#pragma unroll
    for (int ss = 0; ss < 2; ++ss) {
      const int s = 2 * hw + ss;
      float v[8];
      const float* pS = Gh + ((size_t)(g * 128) + s * 16 + mr) * 64 + 8 * il;
#pragma unroll
      for (int j = 0; j < 8; ++j) v[j] = pS[j];
      gA[ss * 6 + 0] = pack8(v);
#pragma unroll
      for (int j = 0; j < 8; ++j) v[j] = pS[32 + j];
      gA[ss * 6 + 1] = pack8(v);
      float e[8] = {0.f,0.f,0.f,0.f,0.f,0.f,0.f,0.f};
      if (il == 0) {
        const int o2 = s * 16 + mr;
        e[0] = Gd[g * 128 + o2];
#pragma unroll
        for (int t4 = 0; t4 < 4; ++t4) e[1 + t4] = Gm[((size_t)(g * 128) + o2) * 4 + t4];
        e[5] = bgd[g * 128 + o2] + bgm[g * 128 + o2] + bgh[g * 128 + o2];
      }
      gA[ss * 6 + 2] = pack8(e);
      const float* pT = pS + 64 * 64;
#pragma unroll
      for (int j = 0; j < 8; ++j) v[j] = pT[j];
      gA[ss * 6 + 3] = pack8(v);
#pragma unroll
      for (int j = 0; j < 8; ++j) v[j] = pT[32 + j];
      gA[ss * 6 + 4] = pack8(v);
      float e2[8] = {0.f,0.f,0.f,0.f,0.f,0.f,0.f,0.f};
      if (il == 0) {
        const int o2 = 64 + s * 16 + mr;
        e2[0] = Gd[g * 128 + o2];
#pragma unroll
        for (int t4 = 0; t4 < 4; ++t4) e2[1 + t4] = Gm[((size_t)(g * 128) + o2) * 4 + t4];
        e2[5] = bgd[g * 128 + o2] + bgm[g * 128 + o2] + bgh[g * 128 + o2];
      }
      gA[ss * 6 + 5] = pack8(e2);
    }

    const int p4 = (w >> 1) * 4;
#pragma unroll
    for (int bci = 0; bci < 4; ++bci) {
      const int bcl = p4 + bci;
      const bh8 b0 = *(const bh8*)(sHid + swz(bcl, mr, 16 * il));
      const bh8 b1 = *(const bh8*)(sHid + swz(bcl, mr, 64 + 16 * il));
      const int bcg = bcT * 16 + bcl;
      const int bb = bcg >> 6, cc_ = bcg & 63;
      const bh8 bx = *(const bh8*)(fg + (size_t)((bb * 96 + r0 + mr) * 64 + cc_) * 8);
#pragma unroll
      for (int ss = 0; ss < 2; ++ss) {
        const int s = 2 * hw + ss;
        fx4 aS = {0.f,0.f,0.f,0.f}, aT = {0.f,0.f,0.f,0.f};
        aS = MFMA16(gA[ss * 6 + 0], b0, aS);
        aS = MFMA16(gA[ss * 6 + 1], b1, aS);
        aS = MFMA16(gA[ss * 6 + 2], bx, aS);
        aT = MFMA16(gA[ss * 6 + 3], b0, aT);
        aT = MFMA16(gA[ss * 6 + 4], b1, aT);
        aT = MFMA16(gA[ss * 6 + 5], bx, aT);
        const sh4 h4 = *(const sh4*)(sHid + swz(bcl, mr, s * 32 + il * 8));
        sh4 o4;
#pragma unroll
        for (int cc = 0; cc < 4; ++cc) {
          const float sig = 1.f / (1.f + __expf(-aS[cc]));
          const float th  = 1.f - 2.f / (1.f + __expf(2.f * aT[cc]));
          const float h   = fmaf(b2f((ushort)h4[cc]), sig, (1.f - sig) * th);
          o4[cc] = (short)f2b(h);
        }
        *(sh4*)(sGat + swz(bcl, mr, s * 32 + il * 8)) = o4;
      }
    }
  }
  __syncthreads();   // B2: sGat complete

  // ---------- fc phase: wave (s4=w&3, hf=w>>2), K = 16pos x 64i split by hf ----------
  {
    const int s4 = w & 3, hf = w >> 2;
    const ushort* fb = FwT + ((size_t)(g * 64 + s4 * 16 + mr) * 96 + r0) * 64;
    fx4 facc = {0.f, 0.f, 0.f, 0.f};
#pragma unroll
    for (int f = 0; f < 16; ++f) {
      const int rr = hf * 8 + (f >> 1);
      const int i0 = (f & 1) * 32;
      const bh8 aF = *(const bh8*)(fb + rr * 64 + i0 + 8 * il);
      const bh8 bF = *(const bh8*)(sGat + swz(mr, rr, i0 * 2 + 16 * il));
      facc = MFMA16(aF, bF, facc);
    }
    float* pp = part + ((size_t)((ch * 2 + hf) * 8 + g) * 32 + bcT) * 1024;
#pragma unroll
    for (int cc = 0; cc < 4; ++cc)
      pp[mr * 64 + s4 * 16 + 4 * il + cc] = facc[cc];
  }
}

// ================= reduce: out = sum of 12 partials + bias =================
__global__ __launch_bounds__(256)
void reduce_k(const float* __restrict__ part, const float* __restrict__ bf,
              float* __restrict__ out)
{
  const int e = blockIdx.x * 256 + threadIdx.x;     // 262144 outputs
  const int o = e & 63, g = (e >> 6) & 7, bcg = e >> 9;
  const int bcT = bcg >> 4, bcl = bcg & 15;
  float s = bf[g * 64 + o];
#pragma unroll
  for (int ch = 0; ch < 6; ++ch)
#pragma unroll
    for (int hf = 0; hf < 2; ++hf)
      s += part[((size_t)((ch * 2 + hf) * 8 + g) * 32 + bcT) * 1024 + bcl * 64 + o];
  out[e] = s;
}

} // namespace

extern "C" void kernel_launch(void* const* d_in, const int* in_sizes, int n_in,
                              void* d_out, int out_size, void* d_ws, size_t ws_size,
                              hipStream_t stream) {
  const float* x   = (const float*)d_in[0];
  const float* xm  = (const float*)d_in[1];
  const float* Wd  = (const float*)d_in[2];
  const float* bd  = (const float*)d_in[3];
  const float* Wm  = (const float*)d_in[4];
  const float* bm  = (const float*)d_in[5];
  const float* Gd  = (const float*)d_in[6];
  const float* bgd = (const float*)d_in[7];
  const float* Gm  = (const float*)d_in[8];
  const float* bgm = (const float*)d_in[9];
  const float* Gh  = (const float*)d_in[10];
  const float* bgh = (const float*)d_in[11];
  const float* Fw  = (const float*)d_in[12];
  const float* bf  = (const float*)d_in[13];
  float* outp = (float*)d_out;

  ushort* feat = (ushort*)((char*)d_ws + FEAT_OFF);
  ushort* FwT  = (ushort*)((char*)d_ws + FWT_OFF);
  ushort* cA   = (ushort*)((char*)d_ws + CA_OFF);
  float*  part = (float*)((char*)d_ws + PART_OFF);

  cvt_k<<<dim3(NPOS / 256 + 512 + 1), dim3(256), 0, stream>>>(
      x, xm, Fw, Wd, bd, Wm, bm, feat, FwT, cA);
  fused_v4<<<dim3(1536), dim3(512), 0, stream>>>(
      Gd, bgd, Gm, bgm, Gh, bgh, feat, FwT, cA, part);
  reduce_k<<<dim3(1024), dim3(256), 0, stream>>>(part, bf, outp);
}

// Round 5
// 167.504 us; speedup vs baseline: 1.0180x; 1.0180x over previous
//
#include <hip/hip_runtime.h>
#include <hip/hip_bf16.h>

namespace {

typedef __attribute__((ext_vector_type(8))) short bh8;   // 8 bf16 = 4 VGPR MFMA A/B frag
typedef __attribute__((ext_vector_type(4))) short sh4;   // 4 bf16 (8B)
typedef __attribute__((ext_vector_type(4))) float fx4;

constexpr int Rn = 96, Cn = 64, CINn = 8, COUTn = 64;
constexpr int NPOS = 8 * 96 * 64 * 8;       // 393216 positions
// ws layout (bytes)
constexpr size_t FEAT_OFF = 0;                                // feat bf16x8 per pos, pos-major: 6.29 MB
constexpr size_t FWT_OFF  = (size_t)NPOS * 16;                // FwT bf16 [g][o][r][i]: 6.29 MB
constexpr size_t CA_OFF   = FWT_OFF + (size_t)NPOS * 16;      // convA bf16 [g][co][64]: 64 KB
constexpr size_t GT_OFF   = CA_OFF + 65536;                   // gate table bf16 [g*128+o2][80]: 160 KB
constexpr size_t PART_OFF = GT_OFF + 163840;                  // partials f32 [3072][1024]: 12.6 MB

__device__ inline ushort f2b(float f) {
  __hip_bfloat16 h = __float2bfloat16(f);
  return __builtin_bit_cast(ushort, h);
}
__device__ inline float b2f(ushort u) {
  return __builtin_bit_cast(float, (unsigned)u << 16);
}
// swizzled byte offset into a [16 bc][16 pos][64 i] bf16 buffer (128B rows)
__device__ inline int swz(int bc, int pos, int ib) {
  return (bc * 2048 + pos * 128 + ib) ^ (((pos + bc) & 7) << 4);
}

#define MFMA16(a, b, c) __builtin_amdgcn_mfma_f32_16x16x32_bf16((a), (b), (c), 0, 0, 0)

// ================= featk: coalesced pos-major feat pack + gate table =================
__global__ __launch_bounds__(256)
void featk(const float* __restrict__ x, const float* __restrict__ xm,
           const float* __restrict__ Gd, const float* __restrict__ bgd,
           const float* __restrict__ Gm, const float* __restrict__ bgm,
           const float* __restrict__ Gh, const float* __restrict__ bgh,
           ushort* __restrict__ feat, ushort* __restrict__ GT)
{
  const int bid = blockIdx.x, t = threadIdx.x;
  if (bid < NPOS / 256) {
    const int pos = bid * 256 + t;
    const float xs = x[pos];
    const fx4 m = *(const fx4*)(xm + (size_t)pos * 4);
    bh8 o;
    o[0] = (short)f2b(xs);
    o[1] = (short)f2b(m[0]); o[2] = (short)f2b(m[1]);
    o[3] = (short)f2b(m[2]); o[4] = (short)f2b(m[3]);
    o[5] = (short)0x3F80; o[6] = 0; o[7] = 0;
    *(bh8*)(feat + (size_t)pos * 8) = o;
  } else {
    // gate table: row ro = g*128 + o2; cols 0..63 = Gh, 64 = Gd, 65..68 = Gm,
    // 69 = bias sum, 70..79 = 0 (cols 72..79 are the il>0 zero frag)
    for (int ro = t; ro < 1024; ro += 256) {
      ushort* row = GT + (size_t)ro * 80;
#pragma unroll
      for (int c = 0; c < 64; ++c) row[c] = f2b(Gh[(size_t)ro * 64 + c]);
      row[64] = f2b(Gd[ro]);
#pragma unroll
      for (int tt = 0; tt < 4; ++tt) row[65 + tt] = f2b(Gm[(size_t)ro * 4 + tt]);
      row[69] = f2b(bgd[ro] + bgm[ro] + bgh[ro]);
#pragma unroll
      for (int c = 70; c < 80; ++c) row[c] = 0;
    }
  }
}

// ================= fwtk: FwT transpose [g][o][r][i] + convA table =================
__global__ __launch_bounds__(256)
void fwtk(const float* __restrict__ Fw, const float* __restrict__ Wd,
          const float* __restrict__ bd, const float* __restrict__ Wm,
          const float* __restrict__ bm, ushort* __restrict__ FwT,
          ushort* __restrict__ cA)
{
  __shared__ float tile[64 * 97];
  const int bid = blockIdx.x, t = threadIdx.x;
  if (bid < 512) {
    const int go = bid;
    const float* src = Fw + (size_t)go * 6144;
    for (int idx = t; idx < 6144; idx += 256) tile[(idx / 96) * 97 + (idx % 96)] = src[idx];
    __syncthreads();
    ushort* dst = FwT + (size_t)go * 6144;
    for (int idx = t; idx < 6144; idx += 256) {
      const int r = idx >> 6, i = idx & 63;
      dst[idx] = f2b(tile[i * 97 + r]);
    }
  } else {
    for (int e = t; e < 32768; e += 256) {
      const int g = e >> 12, co = (e >> 6) & 63, k = e & 63;
      const int tap = k >> 3, tch = k & 7;
      float v = 0.f;
      if (tch == 0)      v = Wd[(g * 64 + co) * 8 + tap];
      else if (tch <= 4) v = Wm[((g * 64 + co) * 4 + (tch - 1)) * 8 + tap];
      else if (tch == 5 && tap == 0) v = bd[g * 64 + co] + bm[g * 64 + co];
      cA[e] = f2b(v);
    }
  }
}

// ================= main: conv -> gate -> fc partial (one 16-row chunk per block) =================
__global__ __launch_bounds__(512, 4)
void fused_v5(const ushort* __restrict__ feat, const ushort* __restrict__ FwT,
              const ushort* __restrict__ cA, const ushort* __restrict__ GT,
              float* __restrict__ part)
{
  __shared__ __align__(16) char sHid[32768];   // [16bc][16pos][64i] bf16, swizzled
  __shared__ __align__(16) char sGat[32768];   // gated hid, same layout

  const int t    = threadIdx.x;
  const int lane = t & 63;
  const int w    = t >> 6;
  const int il   = lane >> 4;
  const int mr   = lane & 15;
  const int bid  = blockIdx.x;
  const int g    = bid & 7;                    // XCD-affine
  const int bcT  = (bid >> 3) & 31;
  const int ch   = bid >> 8;                   // 0..5
  const int r0   = ch * 16;

  // ---------- conv phase: wave w owns bc {2w, 2w+1} ----------
  {
    bh8 aC[4][2];
    const ushort* cAg = cA + g * 4096;
#pragma unroll
    for (int s = 0; s < 4; ++s)
#pragma unroll
      for (int hh = 0; hh < 2; ++hh)
        aC[s][hh] = *(const bh8*)(cAg + (s * 16 + mr) * 64 + hh * 32 + 8 * il);

#pragma unroll
    for (int bci = 0; bci < 2; ++bci) {
      const int bcl = 2 * w + bci;
      const int bcg = bcT * 16 + bcl;
      const int bb = bcg >> 6, cc_ = bcg & 63;
      const int q0 = r0 + mr - 8 + il;
      const int q1 = q0 + 4;
      const bh8 zpad = {0, 0, 0, 0, 0, (short)0x3F80, 0, 0};
      const bh8 b0 = (q0 >= 0)
          ? *(const bh8*)(feat + (size_t)(((bb * 96 + q0) * 64 + cc_) * 8 + g) * 8) : zpad;
      const bh8 b1 = (q1 >= 0)
          ? *(const bh8*)(feat + (size_t)(((bb * 96 + q1) * 64 + cc_) * 8 + g) * 8) : zpad;
#pragma unroll
      for (int s = 0; s < 4; ++s) {
        fx4 a = {0.f, 0.f, 0.f, 0.f};
        a = MFMA16(aC[s][0], b0, a);
        a = MFMA16(aC[s][1], b1, a);
        sh4 o4;
#pragma unroll
        for (int cc = 0; cc < 4; ++cc) o4[cc] = (short)f2b(a[cc]);
        *(sh4*)(sHid + swz(bcl, mr, s * 32 + il * 8)) = o4;
      }
    }
  }
  __syncthreads();   // B1: sHid complete

  // ---------- gate phase: pair p=w>>1 owns bc {4p..4p+3}; half hw=w&1 owns s {2hw,2hw+1} ----------
  {
    const int hw = w & 1;
    const ushort* gtg = GT + (size_t)g * 128 * 80;
    const int xo = (il == 0) ? 64 : 72;          // il>0 lanes read the zero frag
    bh8 gA[12];
#pragma unroll
    for (int ss = 0; ss < 2; ++ss) {
      const int s = 2 * hw + ss;
      const ushort* bs = gtg + (s * 16 + mr) * 80;
      const ushort* bt = gtg + (64 + s * 16 + mr) * 80;
      gA[ss * 6 + 0] = *(const bh8*)(bs + 8 * il);
      gA[ss * 6 + 1] = *(const bh8*)(bs + 32 + 8 * il);
      gA[ss * 6 + 2] = *(const bh8*)(bs + xo);
      gA[ss * 6 + 3] = *(const bh8*)(bt + 8 * il);
      gA[ss * 6 + 4] = *(const bh8*)(bt + 32 + 8 * il);
      gA[ss * 6 + 5] = *(const bh8*)(bt + xo);
    }

    const int p4 = (w >> 1) * 4;
#pragma unroll
    for (int bci = 0; bci < 4; ++bci) {
      const int bcl = p4 + bci;
      const bh8 b0 = *(const bh8*)(sHid + swz(bcl, mr, 16 * il));
      const bh8 b1 = *(const bh8*)(sHid + swz(bcl, mr, 64 + 16 * il));
      const int bcg = bcT * 16 + bcl;
      const int bb = bcg >> 6, cc_ = bcg & 63;
      const bh8 bx = *(const bh8*)(feat + (size_t)(((bb * 96 + r0 + mr) * 64 + cc_) * 8 + g) * 8);
#pragma unroll
      for (int ss = 0; ss < 2; ++ss) {
        const int s = 2 * hw + ss;
        fx4 aS = {0.f,0.f,0.f,0.f}, aT = {0.f,0.f,0.f,0.f};
        aS = MFMA16(gA[ss * 6 + 0], b0, aS);
        aS = MFMA16(gA[ss * 6 + 1], b1, aS);
        aS = MFMA16(gA[ss * 6 + 2], bx, aS);
        aT = MFMA16(gA[ss * 6 + 3], b0, aT);
        aT = MFMA16(gA[ss * 6 + 4], b1, aT);
        aT = MFMA16(gA[ss * 6 + 5], bx, aT);
        const sh4 h4 = *(const sh4*)(sHid + swz(bcl, mr, s * 32 + il * 8));
        sh4 o4;
#pragma unroll
        for (int cc = 0; cc < 4; ++cc) {
          const float sig = 1.f / (1.f + __expf(-aS[cc]));
          const float th  = 1.f - 2.f / (1.f + __expf(2.f * aT[cc]));
          const float h   = fmaf(b2f((ushort)h4[cc]), sig, (1.f - sig) * th);
          o4[cc] = (short)f2b(h);
        }
        *(sh4*)(sGat + swz(bcl, mr, s * 32 + il * 8)) = o4;
      }
    }
  }
  __syncthreads();   // B2: sGat complete

  // ---------- fc phase: wave (s4=w&3, hf=w>>2), K = 16pos x 64i split by hf ----------
  {
    const int s4 = w & 3, hf = w >> 2;
    const ushort* fb = FwT + ((size_t)(g * 64 + s4 * 16 + mr) * 96 + r0) * 64;
    fx4 facc = {0.f, 0.f, 0.f, 0.f};
#pragma unroll
    for (int f = 0; f < 16; ++f) {
      const int rr = hf * 8 + (f >> 1);
      const int i0 = (f & 1) * 32;
      const bh8 aF = *(const bh8*)(fb + rr * 64 + i0 + 8 * il);
      const bh8 bF = *(const bh8*)(sGat + swz(mr, rr, i0 * 2 + 16 * il));
      facc = MFMA16(aF, bF, facc);
    }
    float* pp = part + ((size_t)((ch * 2 + hf) * 8 + g) * 32 + bcT) * 1024;
#pragma unroll
    for (int cc = 0; cc < 4; ++cc)
      pp[mr * 64 + s4 * 16 + 4 * il + cc] = facc[cc];
  }
}

// ================= reduce: out = sum of 12 partials + bias =================
__global__ __launch_bounds__(256)
void reduce_k(const float* __restrict__ part, const float* __restrict__ bf,
              float* __restrict__ out)
{
  const int e = blockIdx.x * 256 + threadIdx.x;     // 262144 outputs
  const int o = e & 63, g = (e >> 6) & 7, bcg = e >> 9;
  const int bcT = bcg >> 4, bcl = bcg & 15;
  float s = bf[g * 64 + o];
#pragma unroll
  for (int ch = 0; ch < 6; ++ch)
#pragma unroll
    for (int hf = 0; hf < 2; ++hf)
      s += part[((size_t)((ch * 2 + hf) * 8 + g) * 32 + bcT) * 1024 + bcl * 64 + o];
  out[e] = s;
}

} // namespace

extern "C" void kernel_launch(void* const* d_in, const int* in_sizes, int n_in,
                              void* d_out, int out_size, void* d_ws, size_t ws_size,
                              hipStream_t stream) {
  const float* x   = (const float*)d_in[0];
  const float* xm  = (const float*)d_in[1];
  const float* Wd  = (const float*)d_in[2];
  const float* bd  = (const float*)d_in[3];
  const float* Wm  = (const float*)d_in[4];
  const float* bm  = (const float*)d_in[5];
  const float* Gd  = (const float*)d_in[6];
  const float* bgd = (const float*)d_in[7];
  const float* Gm  = (const float*)d_in[8];
  const float* bgm = (const float*)d_in[9];
  const float* Gh  = (const float*)d_in[10];
  const float* bgh = (const float*)d_in[11];
  const float* Fw  = (const float*)d_in[12];
  const float* bf  = (const float*)d_in[13];
  float* outp = (float*)d_out;

  ushort* feat = (ushort*)((char*)d_ws + FEAT_OFF);
  ushort* FwT  = (ushort*)((char*)d_ws + FWT_OFF);
  ushort* cA   = (ushort*)((char*)d_ws + CA_OFF);
  ushort* GT   = (ushort*)((char*)d_ws + GT_OFF);
  float*  part = (float*)((char*)d_ws + PART_OFF);

  featk<<<dim3(NPOS / 256 + 1), dim3(256), 0, stream>>>(
      x, xm, Gd, bgd, Gm, bgm, Gh, bgh, feat, GT);
  fwtk<<<dim3(513), dim3(256), 0, stream>>>(Fw, Wd, bd, Wm, bm, FwT, cA);
  fused_v5<<<dim3(1536), dim3(512), 0, stream>>>(feat, FwT, cA, GT, part);
  reduce_k<<<dim3(1024), dim3(256), 0, stream>>>(part, bf, outp);
}

// Round 6
// 78.306 us; speedup vs baseline: 2.1777x; 2.1391x over previous
//
#include <hip/hip_runtime.h>
#include <hip/hip_bf16.h>

namespace {

typedef __attribute__((ext_vector_type(8))) short bh8;   // 8 bf16 = 4 VGPR MFMA A/B frag
typedef __attribute__((ext_vector_type(4))) short sh4;   // 4 bf16 (8B)
typedef __attribute__((ext_vector_type(4))) float fx4;

constexpr int Rn = 96, Cn = 64, CINn = 8, COUTn = 64;
constexpr int NPOS = 8 * 96 * 64 * 8;       // 393216 positions
// ws layout (bytes)
constexpr size_t FEAT_OFF = 0;                                // feat bf16x8 per pos, pos-major: 6.29 MB
constexpr size_t FWT_OFF  = (size_t)NPOS * 16;                // FwT bf16 [g][o][r][i]: 6.29 MB
constexpr size_t CA_OFF   = FWT_OFF + (size_t)NPOS * 16;      // convA bf16 [g][co][64]: 64 KB
constexpr size_t GT_OFF   = CA_OFF + 65536;                   // gate table bf16 [g*128+o2][80]: 160 KB
constexpr size_t PART_OFF = GT_OFF + 163840;                  // partials f32 [3072][1024]: 12.6 MB

__device__ inline ushort f2b(float f) {
  __hip_bfloat16 h = __float2bfloat16(f);
  return __builtin_bit_cast(ushort, h);
}
__device__ inline float b2f(ushort u) {
  return __builtin_bit_cast(float, (unsigned)u << 16);
}
// swizzled byte offset into a [16 bc][16 pos][64 i] bf16 buffer (128B rows)
__device__ inline int swz(int bc, int pos, int ib) {
  return (bc * 2048 + pos * 128 + ib) ^ (((pos + bc) & 7) << 4);
}

#define MFMA16(a, b, c) __builtin_amdgcn_mfma_f32_16x16x32_bf16((a), (b), (c), 0, 0, 0)

// ================= featk: coalesced pos-major feat pack (no tails) =================
__global__ __launch_bounds__(256)
void featk(const float* __restrict__ x, const float* __restrict__ xm,
           ushort* __restrict__ feat)
{
  const int pos = blockIdx.x * 256 + threadIdx.x;
  const float xs = x[pos];
  const fx4 m = *(const fx4*)(xm + (size_t)pos * 4);
  bh8 o;
  o[0] = (short)f2b(xs);
  o[1] = (short)f2b(m[0]); o[2] = (short)f2b(m[1]);
  o[3] = (short)f2b(m[2]); o[4] = (short)f2b(m[3]);
  o[5] = (short)0x3F80; o[6] = 0; o[7] = 0;
  *(bh8*)(feat + (size_t)pos * 8) = o;
}

// ================= tabk: GT + convA tables, one element per thread =================
__global__ __launch_bounds__(256)
void tabk(const float* __restrict__ Gd, const float* __restrict__ bgd,
          const float* __restrict__ Gm, const float* __restrict__ bgm,
          const float* __restrict__ Gh, const float* __restrict__ bgh,
          const float* __restrict__ Wd, const float* __restrict__ bd,
          const float* __restrict__ Wm, const float* __restrict__ bm,
          ushort* __restrict__ GT, ushort* __restrict__ cA)
{
  const int bid = blockIdx.x, t = threadIdx.x;
  if (bid < 320) {
    // GT: row ro = g*128+o2; cols 0..63 = Gh, 64 = Gd, 65..68 = Gm, 69 = bias, 70..79 = 0
    const int idx = bid * 256 + t;            // 81920 elems
    const int ro = idx / 80, c = idx - ro * 80;
    float v = 0.f;
    if (c < 64)       v = Gh[(size_t)ro * 64 + c];
    else if (c == 64) v = Gd[ro];
    else if (c <= 68) v = Gm[(size_t)ro * 4 + (c - 65)];
    else if (c == 69) v = bgd[ro] + bgm[ro] + bgh[ro];
    GT[idx] = f2b(v);
  } else {
    // convA[g][co][k=tap*8+tch]
    const int e = (bid - 320) * 256 + t;      // 32768 elems
    const int g = e >> 12, co = (e >> 6) & 63, k = e & 63;
    const int tap = k >> 3, tch = k & 7;
    float v = 0.f;
    if (tch == 0)      v = Wd[(g * 64 + co) * 8 + tap];
    else if (tch <= 4) v = Wm[((g * 64 + co) * 4 + (tch - 1)) * 8 + tap];
    else if (tch == 5 && tap == 0) v = bd[g * 64 + co] + bm[g * 64 + co];
    cA[e] = f2b(v);
  }
}

// ================= transk: FwT[g][o][r][i] <- Fw[g][o][i][r], unrolled LDS transpose =================
__global__ __launch_bounds__(512)
void transk(const float* __restrict__ Fw, ushort* __restrict__ FwT)
{
  __shared__ float tile[64 * 97];
  const int go = blockIdx.x, t = threadIdx.x;
  const float* src = Fw + (size_t)go * 6144;
  ushort* dst = FwT + (size_t)go * 6144;
#pragma unroll
  for (int it = 0; it < 12; ++it) {
    const int idx = t + it * 512;
    tile[(idx / 96) * 97 + (idx % 96)] = src[idx];
  }
  __syncthreads();
#pragma unroll
  for (int it = 0; it < 12; ++it) {
    const int idx = t + it * 512;
    const int r = idx >> 6, i = idx & 63;
    dst[idx] = f2b(tile[i * 97 + r]);
  }
}

// ================= main: conv -> gate -> fc partial (one 16-row chunk per block) =================
__global__ __launch_bounds__(512, 4)
void fused_v5(const ushort* __restrict__ feat, const ushort* __restrict__ FwT,
              const ushort* __restrict__ cA, const ushort* __restrict__ GT,
              float* __restrict__ part)
{
  __shared__ __align__(16) char sHid[32768];   // [16bc][16pos][64i] bf16, swizzled
  __shared__ __align__(16) char sGat[32768];   // gated hid, same layout

  const int t    = threadIdx.x;
  const int lane = t & 63;
  const int w    = t >> 6;
  const int il   = lane >> 4;
  const int mr   = lane & 15;
  const int bid  = blockIdx.x;
  const int g    = bid & 7;                    // XCD-affine
  const int bcT  = (bid >> 3) & 31;
  const int ch   = bid >> 8;                   // 0..5
  const int r0   = ch * 16;

  // ---------- conv phase: wave w owns bc {2w, 2w+1} ----------
  {
    bh8 aC[4][2];
    const ushort* cAg = cA + g * 4096;
#pragma unroll
    for (int s = 0; s < 4; ++s)
#pragma unroll
      for (int hh = 0; hh < 2; ++hh)
        aC[s][hh] = *(const bh8*)(cAg + (s * 16 + mr) * 64 + hh * 32 + 8 * il);

#pragma unroll
    for (int bci = 0; bci < 2; ++bci) {
      const int bcl = 2 * w + bci;
      const int bcg = bcT * 16 + bcl;
      const int bb = bcg >> 6, cc_ = bcg & 63;
      const int q0 = r0 + mr - 8 + il;
      const int q1 = q0 + 4;
      const bh8 zpad = {0, 0, 0, 0, 0, (short)0x3F80, 0, 0};
      const bh8 b0 = (q0 >= 0)
          ? *(const bh8*)(feat + (size_t)(((bb * 96 + q0) * 64 + cc_) * 8 + g) * 8) : zpad;
      const bh8 b1 = (q1 >= 0)
          ? *(const bh8*)(feat + (size_t)(((bb * 96 + q1) * 64 + cc_) * 8 + g) * 8) : zpad;
#pragma unroll
      for (int s = 0; s < 4; ++s) {
        fx4 a = {0.f, 0.f, 0.f, 0.f};
        a = MFMA16(aC[s][0], b0, a);
        a = MFMA16(aC[s][1], b1, a);
        sh4 o4;
#pragma unroll
        for (int cc = 0; cc < 4; ++cc) o4[cc] = (short)f2b(a[cc]);
        *(sh4*)(sHid + swz(bcl, mr, s * 32 + il * 8)) = o4;
      }
    }
  }
  __syncthreads();   // B1: sHid complete

  // ---------- gate phase: pair p=w>>1 owns bc {4p..4p+3}; half hw=w&1 owns s {2hw,2hw+1} ----------
  {
    const int hw = w & 1;
    const ushort* gtg = GT + (size_t)g * 128 * 80;
    const int xo = (il == 0) ? 64 : 72;          // il>0 lanes read the zero frag
    bh8 gA[12];
#pragma unroll
    for (int ss = 0; ss < 2; ++ss) {
      const int s = 2 * hw + ss;
      const ushort* bs = gtg + (s * 16 + mr) * 80;
      const ushort* bt = gtg + (64 + s * 16 + mr) * 80;
      gA[ss * 6 + 0] = *(const bh8*)(bs + 8 * il);
      gA[ss * 6 + 1] = *(const bh8*)(bs + 32 + 8 * il);
      gA[ss * 6 + 2] = *(const bh8*)(bs + xo);
      gA[ss * 6 + 3] = *(const bh8*)(bt + 8 * il);
      gA[ss * 6 + 4] = *(const bh8*)(bt + 32 + 8 * il);
      gA[ss * 6 + 5] = *(const bh8*)(bt + xo);
    }

    const int p4 = (w >> 1) * 4;
#pragma unroll
    for (int bci = 0; bci < 4; ++bci) {
      const int bcl = p4 + bci;
      const bh8 b0 = *(const bh8*)(sHid + swz(bcl, mr, 16 * il));
      const bh8 b1 = *(const bh8*)(sHid + swz(bcl, mr, 64 + 16 * il));
      const int bcg = bcT * 16 + bcl;
      const int bb = bcg >> 6, cc_ = bcg & 63;
      const bh8 bx = *(const bh8*)(feat + (size_t)(((bb * 96 + r0 + mr) * 64 + cc_) * 8 + g) * 8);
#pragma unroll
      for (int ss = 0; ss < 2; ++ss) {
        const int s = 2 * hw + ss;
        fx4 aS = {0.f,0.f,0.f,0.f}, aT = {0.f,0.f,0.f,0.f};
        aS = MFMA16(gA[ss * 6 + 0], b0, aS);
        aS = MFMA16(gA[ss * 6 + 1], b1, aS);
        aS = MFMA16(gA[ss * 6 + 2], bx, aS);
        aT = MFMA16(gA[ss * 6 + 3], b0, aT);
        aT = MFMA16(gA[ss * 6 + 4], b1, aT);
        aT = MFMA16(gA[ss * 6 + 5], bx, aT);
        const sh4 h4 = *(const sh4*)(sHid + swz(bcl, mr, s * 32 + il * 8));
        sh4 o4;
#pragma unroll
        for (int cc = 0; cc < 4; ++cc) {
          const float sig = 1.f / (1.f + __expf(-aS[cc]));
          const float th  = 1.f - 2.f / (1.f + __expf(2.f * aT[cc]));
          const float h   = fmaf(b2f((ushort)h4[cc]), sig, (1.f - sig) * th);
          o4[cc] = (short)f2b(h);
        }
        *(sh4*)(sGat + swz(bcl, mr, s * 32 + il * 8)) = o4;
      }
    }
  }
  __syncthreads();   // B2: sGat complete

  // ---------- fc phase: wave (s4=w&3, hf=w>>2), K = 16pos x 64i split by hf ----------
  {
    const int s4 = w & 3, hf = w >> 2;
    const ushort* fb = FwT + ((size_t)(g * 64 + s4 * 16 + mr) * 96 + r0) * 64;
    fx4 facc = {0.f, 0.f, 0.f, 0.f};
#pragma unroll
    for (int f = 0; f < 16; ++f) {
      const int rr = hf * 8 + (f >> 1);
      const int i0 = (f & 1) * 32;
      const bh8 aF = *(const bh8*)(fb + rr * 64 + i0 + 8 * il);
      const bh8 bF = *(const bh8*)(sGat + swz(mr, rr, i0 * 2 + 16 * il));
      facc = MFMA16(aF, bF, facc);
    }
    float* pp = part + ((size_t)((ch * 2 + hf) * 8 + g) * 32 + bcT) * 1024;
#pragma unroll
    for (int cc = 0; cc < 4; ++cc)
      pp[mr * 64 + s4 * 16 + 4 * il + cc] = facc[cc];
  }
}

// ================= reduce: out = sum of 12 partials + bias =================
__global__ __launch_bounds__(256)
void reduce_k(const float* __restrict__ part, const float* __restrict__ bf,
              float* __restrict__ out)
{
  const int e = blockIdx.x * 256 + threadIdx.x;     // 262144 outputs
  const int o = e & 63, g = (e >> 6) & 7, bcg = e >> 9;
  const int bcT = bcg >> 4, bcl = bcg & 15;
  float s = bf[g * 64 + o];
#pragma unroll
  for (int ch = 0; ch < 6; ++ch)
#pragma unroll
    for (int hf = 0; hf < 2; ++hf)
      s += part[((size_t)((ch * 2 + hf) * 8 + g) * 32 + bcT) * 1024 + bcl * 64 + o];
  out[e] = s;
}

} // namespace

extern "C" void kernel_launch(void* const* d_in, const int* in_sizes, int n_in,
                              void* d_out, int out_size, void* d_ws, size_t ws_size,
                              hipStream_t stream) {
  const float* x   = (const float*)d_in[0];
  const float* xm  = (const float*)d_in[1];
  const float* Wd  = (const float*)d_in[2];
  const float* bd  = (const float*)d_in[3];
  const float* Wm  = (const float*)d_in[4];
  const float* bm  = (const float*)d_in[5];
  const float* Gd  = (const float*)d_in[6];
  const float* bgd = (const float*)d_in[7];
  const float* Gm  = (const float*)d_in[8];
  const float* bgm = (const float*)d_in[9];
  const float* Gh  = (const float*)d_in[10];
  const float* bgh = (const float*)d_in[11];
  const float* Fw  = (const float*)d_in[12];
  const float* bf  = (const float*)d_in[13];
  float* outp = (float*)d_out;

  ushort* feat = (ushort*)((char*)d_ws + FEAT_OFF);
  ushort* FwT  = (ushort*)((char*)d_ws + FWT_OFF);
  ushort* cA   = (ushort*)((char*)d_ws + CA_OFF);
  ushort* GT   = (ushort*)((char*)d_ws + GT_OFF);
  float*  part = (float*)((char*)d_ws + PART_OFF);

  featk<<<dim3(NPOS / 256), dim3(256), 0, stream>>>(x, xm, feat);
  tabk<<<dim3(448), dim3(256), 0, stream>>>(Gd, bgd, Gm, bgm, Gh, bgh,
                                            Wd, bd, Wm, bm, GT, cA);
  transk<<<dim3(512), dim3(512), 0, stream>>>(Fw, FwT);
  fused_v5<<<dim3(1536), dim3(512), 0, stream>>>(feat, FwT, cA, GT, part);
  reduce_k<<<dim3(1024), dim3(256), 0, stream>>>(part, bf, outp);
}